// Round 1
// baseline (2355.536 us; speedup 1.0000x reference)
//
#include <hip/hip_runtime.h>
#include <math.h>

#define CIN 512
#define HW 25
#define NCLS 10
#define LN2PI_F 1.8378770664093453f

// ---------------------------------------------------------------------------
// Kernel 1: fused conv3x3(pad1) + BN (+sigmoid for the activation branch).
// grid = (256 batches, 17 tiles): tiles 0..15 -> pose channels (32 each),
// tile 16 -> the 32 activation channels. Block = 256 threads.
// Thread mapping: px = t&31 (25 valid), slice = t>>5; each thread computes
// 4 output channels (co = base + slice + 8j).
// ---------------------------------------------------------------------------
__global__ __launch_bounds__(256) void conv_bn_kernel(
    const float* __restrict__ x,
    const float* __restrict__ w_pose,
    const float* __restrict__ w_a,
    const float* __restrict__ bn_p_g, const float* __restrict__ bn_p_b,
    const float* __restrict__ bn_p_m, const float* __restrict__ bn_p_v,
    const float* __restrict__ bn_a_g, const float* __restrict__ bn_a_b,
    const float* __restrict__ bn_a_m, const float* __restrict__ bn_a_v,
    float* __restrict__ pose, float* __restrict__ a_act)
{
    __shared__ __align__(16) float xs[CIN * HW];   // 51.2 KB: full x[b]
    const int b = blockIdx.x;
    const int tile = blockIdx.y;
    const int t = threadIdx.x;

    const float* xb = x + (size_t)b * (CIN * HW);
    for (int f4 = t; f4 < (CIN * HW) / 4; f4 += 256)
        reinterpret_cast<float4*>(xs)[f4] = reinterpret_cast<const float4*>(xb)[f4];
    __syncthreads();

    const int px = t & 31;
    const int slice = t >> 5;
    if (px >= HW) return;                  // no barriers after this point
    const int py = px / 5, qx = px % 5;

    const bool is_pose = (tile < 16);
    const int coBase = is_pose ? tile * 32 : 0;
    const float* __restrict__ wsrc = is_pose ? w_pose : w_a;

    float acc[4] = {0.f, 0.f, 0.f, 0.f};
    for (int ci = 0; ci < CIN; ++ci) {
        float xv[9];
        #pragma unroll
        for (int dy = 0; dy < 3; ++dy) {
            #pragma unroll
            for (int dx = 0; dx < 3; ++dx) {
                const int yy = py + dy - 1, xx = qx + dx - 1;
                const bool ok = (yy >= 0) & (yy < 5) & (xx >= 0) & (xx < 5);
                xv[dy*3+dx] = ok ? xs[ci*25 + yy*5 + xx] : 0.f;
            }
        }
        #pragma unroll
        for (int j = 0; j < 4; ++j) {
            const int co = coBase + slice + 8*j;
            const float* __restrict__ wp = wsrc + ((size_t)co * CIN + ci) * 9;
            float s = 0.f;
            #pragma unroll
            for (int k = 0; k < 9; ++k) s = fmaf(wp[k], xv[k], s);
            acc[j] += s;
        }
    }
    #pragma unroll
    for (int j = 0; j < 4; ++j) {
        const int co = coBase + slice + 8*j;
        float g, bb, mm, vv;
        if (is_pose) { g = bn_p_g[co]; bb = bn_p_b[co]; mm = bn_p_m[co]; vv = bn_p_v[co]; }
        else         { g = bn_a_g[co]; bb = bn_a_b[co]; mm = bn_a_m[co]; vv = bn_a_v[co]; }
        const float scale = g / sqrtf(vv + 1e-5f);
        const float val = (acc[j] - mm) * scale + bb;
        if (is_pose) pose[((size_t)b * 512 + co) * 25 + px] = val;
        else         a_act[((size_t)b * 32 + co) * 25 + px] = 1.f / (1.f + expf(-val));
    }
}

// ---------------------------------------------------------------------------
// Kernel 2: EM routing, one block per batch element. 320 threads = 10 classes
// x 32 a-lanes. m = kk*32 + a, kk = 0..24 looped per thread. Votes v[m,c,:]
// recomputed from LDS pose each pass (state between iterations is only
// mu/sigma/a_out per class). Pose LDS layout [kk][p][a]: conflict-free reads.
// ---------------------------------------------------------------------------
__global__ __launch_bounds__(320) void em_kernel(
    const float* __restrict__ pose,
    const float* __restrict__ a_act,
    const float* __restrict__ Wm,       // (800,10,4,4)
    const float* __restrict__ beta_u,   // (10)
    const float* __restrict__ beta_a,   // (10)
    float* __restrict__ out)            // (256,10)
{
    __shared__ __align__(16) float psh[25 * 512];  // [kk][p][a] 51.2 KB
    __shared__ float aush[800];                    // [kk*32+a]
    __shared__ float lnap_sh[32][NCLS];
    __shared__ float mu_sh[NCLS][16];
    __shared__ float i2s_sh[NCLS][16];
    __shared__ float Kc_sh[NCLS];
    __shared__ float aout_sh[NCLS];

    const int b = blockIdx.x;
    const int t = threadIdx.x;
    const int c = t >> 5;     // class 0..9
    const int a = t & 31;     // input-capsule channel 0..31

    // stage pose[b] swizzled: pose[b, a*16+p, px] -> psh[px*512 + p*32 + a]
    const float* pb = pose + (size_t)b * 12800;
    for (int f = t; f < 12800; f += 320) {
        const int c2 = f / 25, px = f - c2 * 25;
        psh[px * 512 + (c2 & 15) * 32 + (c2 >> 4)] = pb[f];
    }
    const float* ab = a_act + (size_t)b * 800;
    for (int f = t; f < 800; f += 320) {
        const int ci = f / 25, px = f - ci * 25;
        aush[px * 32 + ci] = ab[f];
    }
    __syncthreads();

    const float bu = beta_u[c];
    const float ba = beta_a[c];
    const float lam_tab[3] = {0.01f * (1.f - 0.95f),
                              0.01f * (1.f - 0.95f * 0.95f),
                              0.01f * (1.f - 0.95f * 0.95f * 0.95f)};

    float muL[16], i2sL[16], KcL = 0.f;

    for (int it = 0; it < 3; ++it) {
        float S0 = 0.f, S1[16], S2[16];
        #pragma unroll
        for (int p = 0; p < 16; ++p) { S1[p] = 0.f; S2[p] = 0.f; }

        for (int kk = 0; kk < 25; ++kk) {
            // pose fragment (4x4 matrix, row-major in p)
            float pm[16];
            #pragma unroll
            for (int p = 0; p < 16; ++p) pm[p] = psh[kk * 512 + p * 32 + a];
            const int m = kk * 32 + a;
            const float* wp = Wm + ((size_t)m * NCLS + c) * 16;
            const float4 w0 = reinterpret_cast<const float4*>(wp)[0];
            const float4 w1 = reinterpret_cast<const float4*>(wp)[1];
            const float4 w2 = reinterpret_cast<const float4*>(wp)[2];
            const float4 w3 = reinterpret_cast<const float4*>(wp)[3];
            const float wv[16] = {w0.x,w0.y,w0.z,w0.w, w1.x,w1.y,w1.z,w1.w,
                                  w2.x,w2.y,w2.z,w2.w, w3.x,w3.y,w3.z,w3.w};
            // vote: v = pm(4x4) @ W[m,c](4x4)
            float v[16];
            #pragma unroll
            for (int r = 0; r < 4; ++r) {
                #pragma unroll
                for (int s = 0; s < 4; ++s) {
                    float av = 0.f;
                    #pragma unroll
                    for (int tt = 0; tt < 4; ++tt)
                        av = fmaf(pm[r*4+tt], wv[tt*4+s], av);
                    v[r*4+s] = av;
                }
            }

            float rw;
            if (it == 0) {
                rw = aush[m];                       // r == 1
            } else {
                // ln_ap[m,c] = Kc - sum_p (v-mu)^2 / (2 sigma^2)
                float q = KcL;
                #pragma unroll
                for (int p = 0; p < 16; ++p) {
                    const float d = v[p] - muL[p];
                    q -= d * d * i2sL[p];
                }
                lnap_sh[a][c] = q;
                __syncthreads();
                float mx = lnap_sh[a][0];
                #pragma unroll
                for (int cc = 1; cc < NCLS; ++cc) mx = fmaxf(mx, lnap_sh[a][cc]);
                float den = 0.f;
                #pragma unroll
                for (int cc = 0; cc < NCLS; ++cc) den += expf(lnap_sh[a][cc] - mx);
                __syncthreads();
                const float r = expf(q - mx) / den;
                rw = r * aush[m];
            }
            S0 += rw;
            #pragma unroll
            for (int p = 0; p < 16; ++p) {
                const float rv = rw * v[p];
                S1[p] += rv;
                S2[p] = fmaf(rv, v[p], S2[p]);
            }
        }

        // reduce over the 32 a-lanes of this class (half-wave butterfly)
        #pragma unroll
        for (int off = 16; off >= 1; off >>= 1) {
            S0 += __shfl_xor(S0, off);
            #pragma unroll
            for (int p = 0; p < 16; ++p) {
                S1[p] += __shfl_xor(S1[p], off);
                S2[p] += __shfl_xor(S2[p], off);
            }
        }

        if (a == 0) {
            const float lam = lam_tab[it];
            const float s0e = S0 + 1e-12f;          // r_sum + EPS
            float costsum = 0.f, slg = 0.f;
            float mu_[16], sg_[16];
            #pragma unroll
            for (int p = 0; p < 16; ++p) {
                mu_[p] = S1[p] / s0e;
                const float sg = (S2[p] - 2.f*mu_[p]*S1[p] + mu_[p]*mu_[p]*S0) / s0e
                                 + 1e-12f;
                sg_[p] = sg;
                costsum += bu + 0.5f * logf(sg);
            }
            costsum *= S0;                           // * r_s (no EPS)
            const float aout = 1.f / (1.f + expf(-(lam * (ba - costsum))));
            aout_sh[c] = aout;
            if (it < 2) {
                #pragma unroll
                for (int p = 0; p < 16; ++p) {
                    mu_sh[c][p]  = mu_[p];
                    i2s_sh[c][p] = 0.5f / sg_[p];
                    slg += logf(sg_[p] * LN2PI_F);
                }
                Kc_sh[c] = logf(aout) - 0.5f * slg;
            }
        }
        __syncthreads();
        if (it < 2) {
            #pragma unroll
            for (int p = 0; p < 16; ++p) { muL[p] = mu_sh[c][p]; i2sL[p] = i2s_sh[c][p]; }
            KcL = Kc_sh[c];
        }
    }

    if (t < NCLS) {
        float s = 0.f;
        #pragma unroll
        for (int cc = 0; cc < NCLS; ++cc) s += aout_sh[cc];
        out[b * NCLS + t] = logf(aout_sh[t] / s);
    }
}

// ---------------------------------------------------------------------------
extern "C" void kernel_launch(void* const* d_in, const int* in_sizes, int n_in,
                              void* d_out, int out_size, void* d_ws, size_t ws_size,
                              hipStream_t stream) {
    const float* x      = (const float*)d_in[0];
    const float* w_a    = (const float*)d_in[1];
    const float* w_pose = (const float*)d_in[2];
    const float* bn_a_g = (const float*)d_in[3];
    const float* bn_a_b = (const float*)d_in[4];
    const float* bn_a_m = (const float*)d_in[5];
    const float* bn_a_v = (const float*)d_in[6];
    const float* bn_p_g = (const float*)d_in[7];
    const float* bn_p_b = (const float*)d_in[8];
    const float* bn_p_m = (const float*)d_in[9];
    const float* bn_p_v = (const float*)d_in[10];
    const float* Wm     = (const float*)d_in[11];
    const float* beta_u = (const float*)d_in[12];
    const float* beta_a = (const float*)d_in[13];
    float* out = (float*)d_out;

    float* pose  = (float*)d_ws;                       // 256*512*25 floats
    float* a_act = pose + (size_t)256 * 512 * 25;      // 256*32*25 floats

    dim3 g1(256, 17);
    conv_bn_kernel<<<g1, 256, 0, stream>>>(x, w_pose, w_a,
                                           bn_p_g, bn_p_b, bn_p_m, bn_p_v,
                                           bn_a_g, bn_a_b, bn_a_m, bn_a_v,
                                           pose, a_act);
    em_kernel<<<256, 320, 0, stream>>>(pose, a_act, Wm, beta_u, beta_a, out);
}

// Round 2
// 396.146 us; speedup vs baseline: 5.9461x; 5.9461x over previous
//
#include <hip/hip_runtime.h>
#include <math.h>

#define CIN 512
#define HW 25
#define NCLS 10
#define KDIM 4608            // 512*9
#define NTOT 6400            // 256*25
#define MPAD 640             // 544 rounded to 128 multiple
#define LN2PI_F 1.8378770664093453f

typedef __attribute__((ext_vector_type(8))) short bf16x8;
typedef __attribute__((ext_vector_type(4))) float f32x4;

typedef const __attribute__((address_space(1))) void* gas_ptr;
typedef __attribute__((address_space(3))) void* las_ptr;

__device__ __forceinline__ void async_copy16(const void* g, void* l) {
    __builtin_amdgcn_global_load_lds((gas_ptr)g, (las_ptr)l, 16, 0, 0);
}

__device__ __forceinline__ unsigned short f2bf(float f) {
    unsigned int u = __float_as_uint(f);
    u = (u + 0x7fffu + ((u >> 16) & 1u)) >> 16;   // RNE
    return (unsigned short)u;
}

// ---------------------------------------------------------------------------
// pack_a: weights (w_pose rows 0..511, w_a rows 512..543, zeros 544..639)
// fp32 -> bf16, layout A[row][k], k = ci*9 + dy*3 + dx (matches OIHW flat).
// ---------------------------------------------------------------------------
__global__ __launch_bounds__(256) void pack_a_kernel(
    const float* __restrict__ w_pose, const float* __restrict__ w_a,
    unsigned short* __restrict__ A)
{
    const int c = blockIdx.x * 256 + threadIdx.x;       // 4-float chunk id
    if (c >= MPAD * (KDIM / 4)) return;
    const int row = c / (KDIM / 4);
    const int k4 = (c - row * (KDIM / 4)) * 4;
    float4 v = make_float4(0.f, 0.f, 0.f, 0.f);
    if (row < 512)      v = reinterpret_cast<const float4*>(w_pose + (size_t)row * KDIM + k4)[0];
    else if (row < 544) v = reinterpret_cast<const float4*>(w_a + (size_t)(row - 512) * KDIM + k4)[0];
    short4 o;
    o.x = (short)f2bf(v.x); o.y = (short)f2bf(v.y);
    o.z = (short)f2bf(v.z); o.w = (short)f2bf(v.w);
    reinterpret_cast<short4*>(A + (size_t)c * 4)[0] = o;
}

// ---------------------------------------------------------------------------
// bnprep: fold BN into per-output-row scale/bias. Rows 544..639 -> 0.
// ---------------------------------------------------------------------------
__global__ __launch_bounds__(640) void bnprep_kernel(
    const float* __restrict__ bn_p_g, const float* __restrict__ bn_p_b,
    const float* __restrict__ bn_p_m, const float* __restrict__ bn_p_v,
    const float* __restrict__ bn_a_g, const float* __restrict__ bn_a_b,
    const float* __restrict__ bn_a_m, const float* __restrict__ bn_a_v,
    float* __restrict__ sc, float* __restrict__ bi)
{
    const int i = threadIdx.x;
    float s = 0.f, b = 0.f;
    if (i < 512) {
        s = bn_p_g[i] / sqrtf(bn_p_v[i] + 1e-5f);
        b = bn_p_b[i] - bn_p_m[i] * s;
    } else if (i < 544) {
        const int j = i - 512;
        s = bn_a_g[j] / sqrtf(bn_a_v[j] + 1e-5f);
        b = bn_a_b[j] - bn_a_m[j] * s;
    }
    sc[i] = s; bi[i] = b;
}

// ---------------------------------------------------------------------------
// pack_b: im2col, B[n][k] bf16 with n = b*25+px, k = ci*9+dy*3+dx.
// One block per batch image; x[b] staged in LDS.
// ---------------------------------------------------------------------------
__global__ __launch_bounds__(256) void pack_b_kernel(
    const float* __restrict__ x, unsigned short* __restrict__ B)
{
    __shared__ __align__(16) float xs[CIN * HW];
    const int b = blockIdx.x;
    const int t = threadIdx.x;
    const float4* xb = reinterpret_cast<const float4*>(x + (size_t)b * (CIN * HW));
    for (int f4 = t; f4 < (CIN * HW) / 4; f4 += 256)
        reinterpret_cast<float4*>(xs)[f4] = xb[f4];
    __syncthreads();

    // 25 rows x 576 chunks of 8 k-elements
    for (int w = t; w < 25 * (KDIM / 8); w += 256) {
        const int px = w / (KDIM / 8);
        const int ch = w - px * (KDIM / 8);
        const int py = px / 5, qx = px % 5;
        const int k0 = ch * 8;
        unsigned short v[8];
        #pragma unroll
        for (int j = 0; j < 8; ++j) {
            const int k = k0 + j;
            const int ci = k / 9;
            const int kk = k - ci * 9;
            const int dy = kk / 3, dx = kk - dy * 3;
            const int yy = py + dy - 1, xx = qx + dx - 1;
            const bool ok = (yy >= 0) & (yy < 5) & (xx >= 0) & (xx < 5);
            v[j] = ok ? f2bf(xs[ci * 25 + yy * 5 + xx]) : (unsigned short)0;
        }
        int4 o;
        o.x = (int)v[0] | ((int)v[1] << 16);
        o.y = (int)v[2] | ((int)v[3] << 16);
        o.z = (int)v[4] | ((int)v[5] << 16);
        o.w = (int)v[6] | ((int)v[7] << 16);
        reinterpret_cast<int4*>(B + (size_t)(b * 25 + px) * KDIM + k0)[0] = o;
    }
}

// ---------------------------------------------------------------------------
// gemm: C[m][n] = sum_k A[m][k]*B[n][k], bf16 MFMA 16x16x32, tile 128x128,
// 512 threads = 8 waves (2 m x 4 n), wave tile 64x32. global_load_lds 16B
// staging, LDS layout [kc][row^(kc<<2)][8] (XOR swizzle -> 2-way = free).
// Epilogue: BN fold + sigmoid for a-rows (512..543); rows >=544 dropped.
// ---------------------------------------------------------------------------
__global__ __launch_bounds__(512) void gemm_kernel(
    const unsigned short* __restrict__ A,   // [640][4608]
    const unsigned short* __restrict__ B,   // [6400][4608]
    const float* __restrict__ sc, const float* __restrict__ bi,
    float* __restrict__ C)                  // [544][6400]
{
    __shared__ __align__(16) unsigned short As[4][128][8];   // 8 KB
    __shared__ __align__(16) unsigned short Bs[4][128][8];   // 8 KB
    const int t = threadIdx.x;
    const int m0 = blockIdx.x * 128;
    const int n0 = blockIdx.y * 128;
    const int lane = t & 63, w = t >> 6;
    const int wm = w & 1, wn = w >> 1;          // 2 x 4 wave grid
    const int row = lane & 15, quad = lane >> 4;

    f32x4 acc[4][2] = {};

    // staging: slot s = t in [0,512): kc = s>>7, r = s&127; global row r^(kc<<2)
    const int skc = t >> 7, sr = t & 127;
    const int srow = sr ^ (skc << 2);
    const unsigned short* gA = A + (size_t)(m0 + srow) * KDIM + skc * 8;
    const unsigned short* gB = B + (size_t)(n0 + srow) * KDIM + skc * 8;
    unsigned short* lA = &As[0][0][0] + (size_t)(w * 64) * 8;  // wave-uniform
    unsigned short* lB = &Bs[0][0][0] + (size_t)(w * 64) * 8;

    for (int kt = 0; kt < KDIM / 32; ++kt) {
        __syncthreads();                       // LDS free to overwrite
        async_copy16(gA, lA);
        async_copy16(gB, lB);
        gA += 32; gB += 32;
        __syncthreads();                       // drains vmcnt before barrier

        bf16x8 af[4], bf[2];
        #pragma unroll
        for (int mt = 0; mt < 4; ++mt)
            af[mt] = *reinterpret_cast<const bf16x8*>(
                &As[quad][(wm * 64 + mt * 16 + row) ^ (quad << 2)][0]);
        #pragma unroll
        for (int nt = 0; nt < 2; ++nt)
            bf[nt] = *reinterpret_cast<const bf16x8*>(
                &Bs[quad][(wn * 32 + nt * 16 + row) ^ (quad << 2)][0]);
        #pragma unroll
        for (int mt = 0; mt < 4; ++mt)
            #pragma unroll
            for (int nt = 0; nt < 2; ++nt)
                acc[mt][nt] = __builtin_amdgcn_mfma_f32_16x16x32_bf16(
                    af[mt], bf[nt], acc[mt][nt], 0, 0, 0);
    }

    // epilogue: C/D layout col=lane&15, row=quad*4+reg
    #pragma unroll
    for (int mt = 0; mt < 4; ++mt) {
        const int mbase = m0 + wm * 64 + mt * 16 + quad * 4;
        if (mbase >= 544) continue;
        #pragma unroll
        for (int rg = 0; rg < 4; ++rg) {
            const int m = mbase + rg;
            const float s = sc[m], bb = bi[m];
            const bool is_a = (m >= 512);
            #pragma unroll
            for (int nt = 0; nt < 2; ++nt) {
                const int n = n0 + wn * 32 + nt * 16 + (lane & 15);
                float v = fmaf(acc[mt][nt][rg], s, bb);
                if (is_a) v = 1.f / (1.f + expf(-v));
                C[(size_t)m * NTOT + n] = v;
            }
        }
    }
}

// ---------------------------------------------------------------------------
// EM routing (unchanged math; reads pose/a from the GEMM output C).
// C rows 0..511 = pose channels (BN'd), rows 512..543 = sigmoid activations.
// ---------------------------------------------------------------------------
__global__ __launch_bounds__(320) void em_kernel(
    const float* __restrict__ C,
    const float* __restrict__ Wm,       // (800,10,4,4)
    const float* __restrict__ beta_u,   // (10)
    const float* __restrict__ beta_a,   // (10)
    float* __restrict__ out)            // (256,10)
{
    __shared__ __align__(16) float psh[25 * 512];  // [px][p*32+a] 51.2 KB
    __shared__ float aush[800];
    __shared__ float lnap_sh[32][NCLS];
    __shared__ float mu_sh[NCLS][16];
    __shared__ float i2s_sh[NCLS][16];
    __shared__ float Kc_sh[NCLS];
    __shared__ float aout_sh[NCLS];

    const int b = blockIdx.x;
    const int t = threadIdx.x;
    const int c = t >> 5;
    const int a = t & 31;

    const float* pb = C + (size_t)b * 25;               // row stride NTOT
    for (int f = t; f < 12800; f += 320) {
        const int c2 = f / 25, px = f - c2 * 25;
        psh[px * 512 + (c2 & 15) * 32 + (c2 >> 4)] = pb[(size_t)c2 * NTOT + px];
    }
    const float* ab = C + (size_t)512 * NTOT + (size_t)b * 25;
    for (int f = t; f < 800; f += 320) {
        const int ci = f / 25, px = f - ci * 25;
        aush[px * 32 + ci] = ab[(size_t)ci * NTOT + px];
    }
    __syncthreads();

    const float bu = beta_u[c];
    const float ba = beta_a[c];
    const float lam_tab[3] = {0.01f * (1.f - 0.95f),
                              0.01f * (1.f - 0.95f * 0.95f),
                              0.01f * (1.f - 0.95f * 0.95f * 0.95f)};

    float muL[16], i2sL[16], KcL = 0.f;

    for (int it = 0; it < 3; ++it) {
        float S0 = 0.f, S1[16], S2[16];
        #pragma unroll
        for (int p = 0; p < 16; ++p) { S1[p] = 0.f; S2[p] = 0.f; }

        for (int kk = 0; kk < 25; ++kk) {
            float pm[16];
            #pragma unroll
            for (int p = 0; p < 16; ++p) pm[p] = psh[kk * 512 + p * 32 + a];
            const int m = kk * 32 + a;
            const float* wp = Wm + ((size_t)m * NCLS + c) * 16;
            const float4 w0 = reinterpret_cast<const float4*>(wp)[0];
            const float4 w1 = reinterpret_cast<const float4*>(wp)[1];
            const float4 w2 = reinterpret_cast<const float4*>(wp)[2];
            const float4 w3 = reinterpret_cast<const float4*>(wp)[3];
            const float wv[16] = {w0.x,w0.y,w0.z,w0.w, w1.x,w1.y,w1.z,w1.w,
                                  w2.x,w2.y,w2.z,w2.w, w3.x,w3.y,w3.z,w3.w};
            float v[16];
            #pragma unroll
            for (int r = 0; r < 4; ++r)
                #pragma unroll
                for (int s = 0; s < 4; ++s) {
                    float av = 0.f;
                    #pragma unroll
                    for (int tt = 0; tt < 4; ++tt)
                        av = fmaf(pm[r*4+tt], wv[tt*4+s], av);
                    v[r*4+s] = av;
                }

            float rw;
            if (it == 0) {
                rw = aush[m];
            } else {
                float q = KcL;
                #pragma unroll
                for (int p = 0; p < 16; ++p) {
                    const float d = v[p] - muL[p];
                    q -= d * d * i2sL[p];
                }
                lnap_sh[a][c] = q;
                __syncthreads();
                float mx = lnap_sh[a][0];
                #pragma unroll
                for (int cc = 1; cc < NCLS; ++cc) mx = fmaxf(mx, lnap_sh[a][cc]);
                float den = 0.f;
                #pragma unroll
                for (int cc = 0; cc < NCLS; ++cc) den += expf(lnap_sh[a][cc] - mx);
                __syncthreads();
                const float r = expf(q - mx) / den;
                rw = r * aush[m];
            }
            S0 += rw;
            #pragma unroll
            for (int p = 0; p < 16; ++p) {
                const float rv = rw * v[p];
                S1[p] += rv;
                S2[p] = fmaf(rv, v[p], S2[p]);
            }
        }

        #pragma unroll
        for (int off = 16; off >= 1; off >>= 1) {
            S0 += __shfl_xor(S0, off);
            #pragma unroll
            for (int p = 0; p < 16; ++p) {
                S1[p] += __shfl_xor(S1[p], off);
                S2[p] += __shfl_xor(S2[p], off);
            }
        }

        if (a == 0) {
            const float lam = lam_tab[it];
            const float s0e = S0 + 1e-12f;
            float costsum = 0.f, slg = 0.f;
            float mu_[16], sg_[16];
            #pragma unroll
            for (int p = 0; p < 16; ++p) {
                mu_[p] = S1[p] / s0e;
                const float sg = (S2[p] - 2.f*mu_[p]*S1[p] + mu_[p]*mu_[p]*S0) / s0e
                                 + 1e-12f;
                sg_[p] = sg;
                costsum += bu + 0.5f * logf(sg);
            }
            costsum *= S0;
            const float aout = 1.f / (1.f + expf(-(lam * (ba - costsum))));
            aout_sh[c] = aout;
            if (it < 2) {
                #pragma unroll
                for (int p = 0; p < 16; ++p) {
                    mu_sh[c][p]  = mu_[p];
                    i2s_sh[c][p] = 0.5f / sg_[p];
                    slg += logf(sg_[p] * LN2PI_F);
                }
                Kc_sh[c] = logf(aout) - 0.5f * slg;
            }
        }
        __syncthreads();
        if (it < 2) {
            #pragma unroll
            for (int p = 0; p < 16; ++p) { muL[p] = mu_sh[c][p]; i2sL[p] = i2s_sh[c][p]; }
            KcL = Kc_sh[c];
        }
    }

    if (t < NCLS) {
        float s = 0.f;
        #pragma unroll
        for (int cc = 0; cc < NCLS; ++cc) s += aout_sh[cc];
        out[b * NCLS + t] = logf(aout_sh[t] / s);
    }
}

// ---------------------------------------------------------------------------
extern "C" void kernel_launch(void* const* d_in, const int* in_sizes, int n_in,
                              void* d_out, int out_size, void* d_ws, size_t ws_size,
                              hipStream_t stream) {
    const float* x      = (const float*)d_in[0];
    const float* w_a    = (const float*)d_in[1];
    const float* w_pose = (const float*)d_in[2];
    const float* bn_a_g = (const float*)d_in[3];
    const float* bn_a_b = (const float*)d_in[4];
    const float* bn_a_m = (const float*)d_in[5];
    const float* bn_a_v = (const float*)d_in[6];
    const float* bn_p_g = (const float*)d_in[7];
    const float* bn_p_b = (const float*)d_in[8];
    const float* bn_p_m = (const float*)d_in[9];
    const float* bn_p_v = (const float*)d_in[10];
    const float* Wm     = (const float*)d_in[11];
    const float* beta_u = (const float*)d_in[12];
    const float* beta_a = (const float*)d_in[13];
    float* out = (float*)d_out;

    char* p = (char*)d_ws;
    unsigned short* A  = (unsigned short*)p;  p += (size_t)MPAD * KDIM * 2;   // 5.9 MB
    unsigned short* B  = (unsigned short*)p;  p += (size_t)NTOT * KDIM * 2;   // 59 MB
    float* C  = (float*)p;                    p += (size_t)544 * NTOT * 4;    // 13.9 MB
    float* sc = (float*)p;                    p += MPAD * 4;
    float* bi = (float*)p;                    p += MPAD * 4;

    pack_a_kernel<<<(MPAD * (KDIM / 4) + 255) / 256, 256, 0, stream>>>(w_pose, w_a, A);
    bnprep_kernel<<<1, 640, 0, stream>>>(bn_p_g, bn_p_b, bn_p_m, bn_p_v,
                                         bn_a_g, bn_a_b, bn_a_m, bn_a_v, sc, bi);
    pack_b_kernel<<<256, 256, 0, stream>>>(x, B);
    dim3 gg(MPAD / 128, NTOT / 128);
    gemm_kernel<<<gg, 512, 0, stream>>>(A, B, sc, bi, C);
    em_kernel<<<256, 320, 0, stream>>>(C, Wm, beta_u, beta_a, out);
}

// Round 3
// 357.765 us; speedup vs baseline: 6.5840x; 1.1073x over previous
//
#include <hip/hip_runtime.h>
#include <math.h>

#define CIN 512
#define NCLS 10
#define KDIM 4608            // 512*9
#define NTOT 6400            // 256*25
#define MPAD 640
#define BK 128
#define LN2PI_F 1.8378770664093453f

typedef __attribute__((ext_vector_type(8))) short bf16x8;
typedef __attribute__((ext_vector_type(4))) float f32x4;

typedef const __attribute__((address_space(1))) void* gas_ptr;
typedef __attribute__((address_space(3))) void* las_ptr;

__device__ __forceinline__ void async_copy16(const void* g, void* l) {
    __builtin_amdgcn_global_load_lds((gas_ptr)g, (las_ptr)l, 16, 0, 0);
}

__device__ __forceinline__ unsigned short f2bf(float f) {
    unsigned int u = __float_as_uint(f);
    u = (u + 0x7fffu + ((u >> 16) & 1u)) >> 16;   // RNE
    return (unsigned short)u;
}
__device__ __forceinline__ float fexp(float x) { return __expf(x); }
__device__ __forceinline__ float flog(float x) { return __logf(x); }

// ---------------------------------------------------------------------------
// pack_a: weights fp32 -> bf16, A[row][k]; rows 544..639 zero.
// ---------------------------------------------------------------------------
__global__ __launch_bounds__(256) void pack_a_kernel(
    const float* __restrict__ w_pose, const float* __restrict__ w_a,
    unsigned short* __restrict__ A)
{
    const int cid = blockIdx.x * 256 + threadIdx.x;
    if (cid >= MPAD * (KDIM / 4)) return;
    const int row = cid / (KDIM / 4);
    const int k4 = (cid - row * (KDIM / 4)) * 4;
    float4 v = make_float4(0.f, 0.f, 0.f, 0.f);
    if (row < 512)      v = reinterpret_cast<const float4*>(w_pose + (size_t)row * KDIM + k4)[0];
    else if (row < 544) v = reinterpret_cast<const float4*>(w_a + (size_t)(row - 512) * KDIM + k4)[0];
    short4 o;
    o.x = (short)f2bf(v.x); o.y = (short)f2bf(v.y);
    o.z = (short)f2bf(v.z); o.w = (short)f2bf(v.w);
    reinterpret_cast<short4*>(A + (size_t)cid * 4)[0] = o;
}

// ---------------------------------------------------------------------------
__global__ __launch_bounds__(640) void bnprep_kernel(
    const float* __restrict__ bn_p_g, const float* __restrict__ bn_p_b,
    const float* __restrict__ bn_p_m, const float* __restrict__ bn_p_v,
    const float* __restrict__ bn_a_g, const float* __restrict__ bn_a_b,
    const float* __restrict__ bn_a_m, const float* __restrict__ bn_a_v,
    float* __restrict__ sc, float* __restrict__ bi)
{
    const int i = threadIdx.x;
    float s = 0.f, b = 0.f;
    if (i < 512) {
        s = bn_p_g[i] / sqrtf(bn_p_v[i] + 1e-5f);
        b = bn_p_b[i] - bn_p_m[i] * s;
    } else if (i < 544) {
        const int j = i - 512;
        s = bn_a_g[j] / sqrtf(bn_a_v[j] + 1e-5f);
        b = bn_a_b[j] - bn_a_m[j] * s;
    }
    sc[i] = s; bi[i] = b;
}

// ---------------------------------------------------------------------------
// pack_b: im2col fp32->bf16, B[n][k], n = b*25+px, k = ci*9+dy*3+dx.
// ---------------------------------------------------------------------------
__global__ __launch_bounds__(256) void pack_b_kernel(
    const float* __restrict__ x, unsigned short* __restrict__ B)
{
    __shared__ __align__(16) float xs[CIN * 25];
    const int b = blockIdx.x;
    const int t = threadIdx.x;
    const float4* xb = reinterpret_cast<const float4*>(x + (size_t)b * (CIN * 25));
    for (int f4 = t; f4 < (CIN * 25) / 4; f4 += 256)
        reinterpret_cast<float4*>(xs)[f4] = xb[f4];
    __syncthreads();

    for (int w = t; w < 25 * (KDIM / 8); w += 256) {
        const int px = w / (KDIM / 8);
        const int ch = w - px * (KDIM / 8);
        const int py = px / 5, qx = px % 5;
        const int k0 = ch * 8;
        unsigned short v[8];
        #pragma unroll
        for (int j = 0; j < 8; ++j) {
            const int k = k0 + j;
            const int ci = k / 9;
            const int kk = k - ci * 9;
            const int dy = kk / 3, dx = kk - dy * 3;
            const int yy = py + dy - 1, xx = qx + dx - 1;
            const bool ok = (yy >= 0) & (yy < 5) & (xx >= 0) & (xx < 5);
            v[j] = ok ? f2bf(xs[ci * 25 + yy * 5 + xx]) : (unsigned short)0;
        }
        int4 o;
        o.x = (int)v[0] | ((int)v[1] << 16);
        o.y = (int)v[2] | ((int)v[3] << 16);
        o.z = (int)v[4] | ((int)v[5] << 16);
        o.w = (int)v[6] | ((int)v[7] << 16);
        reinterpret_cast<int4*>(B + (size_t)(b * 25 + px) * KDIM + k0)[0] = o;
    }
}

// ---------------------------------------------------------------------------
// gemm: 128x128 tile, 512 threads = 8 waves in 2 K-groups x (2m x 2n) wave
// grid; wave tile 64x64 (4x4 f32x4 acc). BK=128 per barrier-pair (36 iters).
// LDS [kc8][row^(kc8<<2)][8] bf16, 32KB A + 32KB B. K-groups merged via LDS.
// ---------------------------------------------------------------------------
__global__ __launch_bounds__(512) void gemm_kernel(
    const unsigned short* __restrict__ A,   // [640][4608]
    const unsigned short* __restrict__ B,   // [6400][4608]
    const float* __restrict__ sc, const float* __restrict__ bi,
    float* __restrict__ C)                  // [544][6400]
{
    __shared__ __align__(16) unsigned char smem[65536];
    unsigned short* As = (unsigned short*)smem;            // [16][128][8]
    unsigned short* Bs = (unsigned short*)(smem + 32768);  // [16][128][8]

    const int t = threadIdx.x;
    const int m0 = blockIdx.x * 128, n0 = blockIdx.y * 128;
    const int lane = t & 63, w = t >> 6;
    const int g = w >> 2, wq = w & 3;
    const int wm = wq >> 1, wn = wq & 1;
    const int row16 = lane & 15, quad = lane >> 4;

    f32x4 acc[4][4] = {};

    // staging: chunk id = j*512 + t ; kc8 = id>>7, slot row = id&127,
    // global row = slot ^ (kc8<<2). LDS dest = wave-uniform + lane*16.
    const int tb = t >> 7, rr = t & 127;
    const unsigned short* gA[4];
    const unsigned short* gB[4];
    unsigned short* lA[4];
    unsigned short* lB[4];
    #pragma unroll
    for (int j = 0; j < 4; ++j) {
        const int kc8 = j * 4 + tb;
        const int srow = rr ^ (kc8 << 2);
        gA[j] = A + (size_t)(m0 + srow) * KDIM + kc8 * 8;
        gB[j] = B + (size_t)(n0 + srow) * KDIM + kc8 * 8;
        lA[j] = As + (size_t)(j * 512 + w * 64) * 8;
        lB[j] = Bs + (size_t)(j * 512 + w * 64) * 8;
    }

    for (int kt = 0; kt < KDIM / BK; ++kt) {
        __syncthreads();                         // prev-iter reads done
        #pragma unroll
        for (int j = 0; j < 4; ++j) {
            async_copy16(gA[j], lA[j]);
            async_copy16(gB[j], lB[j]);
            gA[j] += BK; gB[j] += BK;
        }
        __syncthreads();                         // drain vmcnt
        #pragma unroll
        for (int ks = 0; ks < 2; ++ks) {
            const int kc8b = (g * 2 + ks) * 4 + quad;
            const int sw = kc8b << 2;
            bf16x8 af[4], bfr[4];
            #pragma unroll
            for (int mt = 0; mt < 4; ++mt)
                af[mt] = *reinterpret_cast<const bf16x8*>(
                    &As[((size_t)kc8b * 128 + ((wm * 64 + mt * 16 + row16) ^ sw)) * 8]);
            #pragma unroll
            for (int nt = 0; nt < 4; ++nt)
                bfr[nt] = *reinterpret_cast<const bf16x8*>(
                    &Bs[((size_t)kc8b * 128 + ((wn * 64 + nt * 16 + row16) ^ sw)) * 8]);
            #pragma unroll
            for (int mt = 0; mt < 4; ++mt)
                #pragma unroll
                for (int nt = 0; nt < 4; ++nt)
                    acc[mt][nt] = __builtin_amdgcn_mfma_f32_16x16x32_bf16(
                        af[mt], bfr[nt], acc[mt][nt], 0, 0, 0);
        }
    }

    // merge K-groups: wave pairs (g0,wq) <- (g1,wq), 2 rounds of 2 pairs.
    float* mb = (float*)smem;                    // 8192 floats
    #pragma unroll
    for (int rnd = 0; rnd < 2; ++rnd) {
        __syncthreads();
        if (g == 1 && (wq >> 1) == rnd) {
            f32x4* dst = (f32x4*)(mb + (wq & 1) * 4096);
            #pragma unroll
            for (int i = 0; i < 16; ++i)
                dst[i * 64 + lane] = acc[i >> 2][i & 3];
        }
        __syncthreads();
        if (g == 0 && (wq >> 1) == rnd) {
            const f32x4* src = (const f32x4*)(mb + (wq & 1) * 4096);
            #pragma unroll
            for (int i = 0; i < 16; ++i)
                acc[i >> 2][i & 3] += src[i * 64 + lane];
        }
    }

    if (g == 0) {
        #pragma unroll
        for (int mt = 0; mt < 4; ++mt) {
            const int mbase = m0 + wm * 64 + mt * 16 + quad * 4;
            if (mbase >= 544) continue;
            #pragma unroll
            for (int rg = 0; rg < 4; ++rg) {
                const int m = mbase + rg;
                const float s = sc[m], bbx = bi[m];
                const bool is_a = (m >= 512);
                #pragma unroll
                for (int nt = 0; nt < 4; ++nt) {
                    const int n = n0 + wn * 64 + nt * 16 + row16;
                    float v = fmaf(acc[mt][nt][rg], s, bbx);
                    if (is_a) v = 1.f / (1.f + fexp(-v));
                    C[(size_t)m * NTOT + n] = v;
                }
            }
        }
    }
}

// ---------------------------------------------------------------------------
// EM routing: 320 threads = 10 classes x 32 a-lanes, one block per batch.
// Phase A writes ln_ap[c][m] for all kk (1 barrier), phase B does the
// cross-class softmax + stats (votes recomputed). ~8 barriers total.
// Pose LDS [kk][a][20]: frag = 4x ds_read_b128, conflict-free (pad 20).
// ---------------------------------------------------------------------------
__global__ __launch_bounds__(320) void em_kernel(
    const float* __restrict__ C,
    const float* __restrict__ Wm,       // (800,10,4,4)
    const float* __restrict__ beta_u, const float* __restrict__ beta_a,
    float* __restrict__ out)            // (256,10)
{
    __shared__ __align__(16) float psh[25][32][20];   // 64 KB
    __shared__ float aush[800];
    __shared__ float lnq[NCLS][800];                  // 32 KB
    __shared__ float mu_sh[NCLS][16];
    __shared__ float i2s_sh[NCLS][16];
    __shared__ float Kc_sh[NCLS];
    __shared__ float aout_sh[NCLS];

    const int b = blockIdx.x, t = threadIdx.x;
    const int c = t >> 5, a = t & 31;

    const float* pb = C + (size_t)b * 25;
    for (int f = t; f < 12800; f += 320) {
        const int c2 = f / 25, px = f - c2 * 25;
        psh[px][c2 >> 4][c2 & 15] = pb[(size_t)c2 * NTOT + px];
    }
    const float* ab = C + (size_t)512 * NTOT + (size_t)b * 25;
    for (int f = t; f < 800; f += 320) {
        const int ci = f / 25, px = f - ci * 25;
        aush[px * 32 + ci] = ab[(size_t)ci * NTOT + px];
    }
    __syncthreads();

    const float bu = beta_u[c], ba = beta_a[c];
    const float lam_tab[3] = {0.01f * (1.f - 0.95f),
                              0.01f * (1.f - 0.95f * 0.95f),
                              0.01f * (1.f - 0.95f * 0.95f * 0.95f)};
    float muL[16], i2sL[16], KcL = 0.f;
    float S0, S1[16], S2[16];

    #define LOAD_VOTE(kk)                                                     \
        float pm[16], vv[16];                                                 \
        {                                                                     \
            const float4* pr = reinterpret_cast<const float4*>(&psh[kk][a][0]);\
            float4 p0 = pr[0], p1 = pr[1], p2 = pr[2], p3 = pr[3];            \
            pm[0]=p0.x; pm[1]=p0.y; pm[2]=p0.z; pm[3]=p0.w;                   \
            pm[4]=p1.x; pm[5]=p1.y; pm[6]=p1.z; pm[7]=p1.w;                   \
            pm[8]=p2.x; pm[9]=p2.y; pm[10]=p2.z; pm[11]=p2.w;                 \
            pm[12]=p3.x; pm[13]=p3.y; pm[14]=p3.z; pm[15]=p3.w;               \
            const float* wp = Wm + ((size_t)((kk)*32 + a) * NCLS + c) * 16;   \
            const float4 w0 = reinterpret_cast<const float4*>(wp)[0];         \
            const float4 w1 = reinterpret_cast<const float4*>(wp)[1];         \
            const float4 w2 = reinterpret_cast<const float4*>(wp)[2];         \
            const float4 w3 = reinterpret_cast<const float4*>(wp)[3];         \
            const float wv[16] = {w0.x,w0.y,w0.z,w0.w, w1.x,w1.y,w1.z,w1.w,   \
                                  w2.x,w2.y,w2.z,w2.w, w3.x,w3.y,w3.z,w3.w};  \
            _Pragma("unroll")                                                 \
            for (int r = 0; r < 4; ++r) {                                     \
                _Pragma("unroll")                                             \
                for (int s = 0; s < 4; ++s) {                                 \
                    float av = 0.f;                                           \
                    _Pragma("unroll")                                         \
                    for (int tt = 0; tt < 4; ++tt)                            \
                        av = fmaf(pm[r*4+tt], wv[tt*4+s], av);                \
                    vv[r*4+s] = av;                                           \
                }                                                             \
            }                                                                 \
        }

    #define ACCUM(rw)                                                        \
        S0 += (rw);                                                          \
        _Pragma("unroll")                                                    \
        for (int p = 0; p < 16; ++p) {                                       \
            const float rv = (rw) * vv[p];                                   \
            S1[p] += rv;                                                     \
            S2[p] = fmaf(rv, vv[p], S2[p]);                                  \
        }

    for (int it = 0; it < 3; ++it) {
        if (it > 0) {
            // phase A: ln_ap for all m
            for (int kk = 0; kk < 25; ++kk) {
                LOAD_VOTE(kk);
                float q = KcL;
                #pragma unroll
                for (int p = 0; p < 16; ++p) {
                    const float d = vv[p] - muL[p];
                    q -= d * d * i2sL[p];
                }
                lnq[c][kk * 32 + a] = q;
            }
            __syncthreads();
        }

        S0 = 0.f;
        #pragma unroll
        for (int p = 0; p < 16; ++p) { S1[p] = 0.f; S2[p] = 0.f; }

        if (it == 0) {
            for (int kk = 0; kk < 25; ++kk) {
                LOAD_VOTE(kk);
                const float rw = aush[kk * 32 + a];
                ACCUM(rw);
            }
        } else {
            for (int kk = 0; kk < 25; ++kk) {
                LOAD_VOTE(kk);
                const int m = kk * 32 + a;
                float qv[NCLS];
                #pragma unroll
                for (int cc = 0; cc < NCLS; ++cc) qv[cc] = lnq[cc][m];
                float mx = qv[0];
                #pragma unroll
                for (int cc = 1; cc < NCLS; ++cc) mx = fmaxf(mx, qv[cc]);
                float den = 0.f;
                #pragma unroll
                for (int cc = 0; cc < NCLS; ++cc) den += fexp(qv[cc] - mx);
                const float r = fexp(qv[c] - mx) * __builtin_amdgcn_rcpf(den);
                const float rw = r * aush[m];
                ACCUM(rw);
            }
        }

        // butterfly over the 32 a-lanes (stays within half-wave)
        #pragma unroll
        for (int off = 16; off >= 1; off >>= 1) {
            S0 += __shfl_xor(S0, off);
            #pragma unroll
            for (int p = 0; p < 16; ++p) {
                S1[p] += __shfl_xor(S1[p], off);
                S2[p] += __shfl_xor(S2[p], off);
            }
        }

        if (a == 0) {
            const float lam = lam_tab[it];
            const float s0e = S0 + 1e-12f;
            const float inv = 1.f / s0e;
            float costsum = 0.f, slg = 0.f;
            float mu_[16], sg_[16];
            #pragma unroll
            for (int p = 0; p < 16; ++p) {
                mu_[p] = S1[p] * inv;
                const float sg = (S2[p] - 2.f * mu_[p] * S1[p] + mu_[p] * mu_[p] * S0) * inv
                                 + 1e-12f;
                sg_[p] = sg;
                costsum += bu + 0.5f * flog(sg);
            }
            costsum *= S0;
            const float aout = 1.f / (1.f + fexp(-(lam * (ba - costsum))));
            aout_sh[c] = aout;
            if (it < 2) {
                #pragma unroll
                for (int p = 0; p < 16; ++p) {
                    mu_sh[c][p] = mu_[p];
                    i2s_sh[c][p] = 0.5f / sg_[p];
                    slg += flog(sg_[p] * LN2PI_F);
                }
                Kc_sh[c] = flog(aout) - 0.5f * slg;
            }
        }
        __syncthreads();
        if (it < 2) {
            #pragma unroll
            for (int p = 0; p < 16; ++p) { muL[p] = mu_sh[c][p]; i2sL[p] = i2s_sh[c][p]; }
            KcL = Kc_sh[c];
        }
    }

    if (t < NCLS) {
        float s = 0.f;
        #pragma unroll
        for (int cc = 0; cc < NCLS; ++cc) s += aout_sh[cc];
        out[b * NCLS + t] = flog(aout_sh[t] / s);
    }
    #undef LOAD_VOTE
    #undef ACCUM
}

// ---------------------------------------------------------------------------
extern "C" void kernel_launch(void* const* d_in, const int* in_sizes, int n_in,
                              void* d_out, int out_size, void* d_ws, size_t ws_size,
                              hipStream_t stream) {
    const float* x      = (const float*)d_in[0];
    const float* w_a    = (const float*)d_in[1];
    const float* w_pose = (const float*)d_in[2];
    const float* bn_a_g = (const float*)d_in[3];
    const float* bn_a_b = (const float*)d_in[4];
    const float* bn_a_m = (const float*)d_in[5];
    const float* bn_a_v = (const float*)d_in[6];
    const float* bn_p_g = (const float*)d_in[7];
    const float* bn_p_b = (const float*)d_in[8];
    const float* bn_p_m = (const float*)d_in[9];
    const float* bn_p_v = (const float*)d_in[10];
    const float* Wm     = (const float*)d_in[11];
    const float* beta_u = (const float*)d_in[12];
    const float* beta_a = (const float*)d_in[13];
    float* out = (float*)d_out;

    char* p = (char*)d_ws;
    unsigned short* A  = (unsigned short*)p;  p += (size_t)MPAD * KDIM * 2;
    unsigned short* B  = (unsigned short*)p;  p += (size_t)NTOT * KDIM * 2;
    float* C  = (float*)p;                    p += (size_t)544 * NTOT * 4;
    float* sc = (float*)p;                    p += MPAD * 4;
    float* bi = (float*)p;                    p += MPAD * 4;

    pack_a_kernel<<<(MPAD * (KDIM / 4) + 255) / 256, 256, 0, stream>>>(w_pose, w_a, A);
    bnprep_kernel<<<1, 640, 0, stream>>>(bn_p_g, bn_p_b, bn_p_m, bn_p_v,
                                         bn_a_g, bn_a_b, bn_a_m, bn_a_v, sc, bi);
    pack_b_kernel<<<256, 256, 0, stream>>>(x, B);
    dim3 gg(MPAD / 128, NTOT / 128);
    gemm_kernel<<<gg, 512, 0, stream>>>(A, B, sc, bi, C);
    em_kernel<<<256, 320, 0, stream>>>(C, Wm, beta_u, beta_a, out);
}

// Round 4
// 293.834 us; speedup vs baseline: 8.0166x; 1.2176x over previous
//
#include <hip/hip_runtime.h>
#include <math.h>

#define CIN 512
#define NCLS 10
#define KDIM 4608            // 512*9
#define NTOT 6400            // 256*25
#define MPAD 640
#define BK 128
#define NKT 36               // KDIM/BK
#define LN2PI_F 1.8378770664093453f

typedef __attribute__((ext_vector_type(8))) short bf16x8;
typedef __attribute__((ext_vector_type(4))) float f32x4;

typedef const __attribute__((address_space(1))) void* gas_ptr;
typedef __attribute__((address_space(3))) void* las_ptr;

__device__ __forceinline__ void async_copy16(const void* g, void* l) {
    __builtin_amdgcn_global_load_lds((gas_ptr)g, (las_ptr)l, 16, 0, 0);
}

__device__ __forceinline__ unsigned short f2bf(float f) {
    unsigned int u = __float_as_uint(f);
    u = (u + 0x7fffu + ((u >> 16) & 1u)) >> 16;   // RNE
    return (unsigned short)u;
}
__device__ __forceinline__ float fexp(float x) { return __expf(x); }
__device__ __forceinline__ float flog(float x) { return __logf(x); }

// ---------------------------------------------------------------------------
// pack_a: weights fp32 -> bf16 into PRE-TILED layout matching the GEMM's LDS
// staging order. Tile (mblk,kt) has 2048 chunks of 8 bf16; chunk c holds
// A[m0 + ((c&127) ^ ((c>>7)<<2))][(kt*16 + (c>>7))*8 ...+8].
// Block 0 additionally computes the folded BN scale/bias.
// ---------------------------------------------------------------------------
__global__ __launch_bounds__(256) void pack_a_kernel(
    const float* __restrict__ w_pose, const float* __restrict__ w_a,
    const float* __restrict__ bn_p_g, const float* __restrict__ bn_p_b,
    const float* __restrict__ bn_p_m, const float* __restrict__ bn_p_v,
    const float* __restrict__ bn_a_g, const float* __restrict__ bn_a_b,
    const float* __restrict__ bn_a_m, const float* __restrict__ bn_a_v,
    unsigned short* __restrict__ At, float* __restrict__ sc, float* __restrict__ bi)
{
    const int blk = blockIdx.x;                  // = mblk*NKT + kt
    const int mblk = blk / NKT;
    const int t = threadIdx.x;

    if (blk == 0) {
        for (int i = t; i < MPAD; i += 256) {
            float s = 0.f, b = 0.f;
            if (i < 512) {
                s = bn_p_g[i] / sqrtf(bn_p_v[i] + 1e-5f);
                b = bn_p_b[i] - bn_p_m[i] * s;
            } else if (i < 544) {
                const int j = i - 512;
                s = bn_a_g[j] / sqrtf(bn_a_v[j] + 1e-5f);
                b = bn_a_b[j] - bn_a_m[j] * s;
            }
            sc[i] = s; bi[i] = b;
        }
    }

    const int kt = blk - mblk * NKT;
    #pragma unroll
    for (int j = 0; j < 8; ++j) {
        const int c = t + j * 256;               // 0..2047
        const int kc8 = c >> 7, slot = c & 127;
        const int row = mblk * 128 + (slot ^ (kc8 << 2));
        const int k0 = (kt * 16 + kc8) * 8;
        float v[8] = {0.f,0.f,0.f,0.f,0.f,0.f,0.f,0.f};
        if (row < 512) {
            const float4* s4 = reinterpret_cast<const float4*>(w_pose + (size_t)row * KDIM + k0);
            float4 x0 = s4[0], x1 = s4[1];
            v[0]=x0.x; v[1]=x0.y; v[2]=x0.z; v[3]=x0.w;
            v[4]=x1.x; v[5]=x1.y; v[6]=x1.z; v[7]=x1.w;
        } else if (row < 544) {
            const float4* s4 = reinterpret_cast<const float4*>(w_a + (size_t)(row - 512) * KDIM + k0);
            float4 x0 = s4[0], x1 = s4[1];
            v[0]=x0.x; v[1]=x0.y; v[2]=x0.z; v[3]=x0.w;
            v[4]=x1.x; v[5]=x1.y; v[6]=x1.z; v[7]=x1.w;
        }
        int4 o;
        o.x = (int)f2bf(v[0]) | ((int)f2bf(v[1]) << 16);
        o.y = (int)f2bf(v[2]) | ((int)f2bf(v[3]) << 16);
        o.z = (int)f2bf(v[4]) | ((int)f2bf(v[5]) << 16);
        o.w = (int)f2bf(v[6]) | ((int)f2bf(v[7]) << 16);
        reinterpret_cast<int4*>(At + ((((size_t)blk) << 11) + c) * 8)[0] = o;
    }
}

// ---------------------------------------------------------------------------
// pack_b: im2col fp32->bf16 into the same pre-tiled layout.
// n = b*25+px, k = ci*9+dy*3+dx. Stores are scattered 16B (fire-and-forget).
// ---------------------------------------------------------------------------
__global__ __launch_bounds__(256) void pack_b_kernel(
    const float* __restrict__ x, unsigned short* __restrict__ Bt)
{
    __shared__ __align__(16) float xs[CIN * 25];
    const int b = blockIdx.x;
    const int t = threadIdx.x;
    const float4* xb = reinterpret_cast<const float4*>(x + (size_t)b * (CIN * 25));
    for (int f4 = t; f4 < (CIN * 25) / 4; f4 += 256)
        reinterpret_cast<float4*>(xs)[f4] = xb[f4];
    __syncthreads();

    for (int w = t; w < 25 * (KDIM / 8); w += 256) {
        const int px = w / (KDIM / 8);
        const int ch = w - px * (KDIM / 8);
        const int py = px / 5, qx = px % 5;
        const int k0 = ch * 8;
        unsigned short v[8];
        #pragma unroll
        for (int j = 0; j < 8; ++j) {
            const int k = k0 + j;
            const int ci = k / 9;
            const int kk = k - ci * 9;
            const int dy = kk / 3, dx = kk - dy * 3;
            const int yy = py + dy - 1, xx = qx + dx - 1;
            const bool ok = (yy >= 0) & (yy < 5) & (xx >= 0) & (xx < 5);
            v[j] = ok ? f2bf(xs[ci * 25 + yy * 5 + xx]) : (unsigned short)0;
        }
        int4 o;
        o.x = (int)v[0] | ((int)v[1] << 16);
        o.y = (int)v[2] | ((int)v[3] << 16);
        o.z = (int)v[4] | ((int)v[5] << 16);
        o.w = (int)v[6] | ((int)v[7] << 16);
        const int n = b * 25 + px;
        const int nblk = n >> 7, nr = n & 127;
        const int kt = k0 >> 7;
        const int kc8 = (k0 >> 3) & 15;
        const int c = kc8 * 128 + (nr ^ (kc8 << 2));
        reinterpret_cast<int4*>(Bt + ((((size_t)(nblk * NKT + kt)) << 11) + c) * 8)[0] = o;
    }
}

// ---------------------------------------------------------------------------
// gemm: 128x128 tile, 512 threads = 2 K-groups x (2m x 2n) waves, wave tile
// 64x64. BK=128, DOUBLE-BUFFERED (2 x 64 KB LDS). Staging from pre-tiled
// A/B: perfectly coalesced 16B-lane streams. One barrier per K-iter;
// prefetch issued after the barrier has the whole compute phase to land.
// ---------------------------------------------------------------------------
__global__ __launch_bounds__(512) void gemm_kernel(
    const unsigned short* __restrict__ At,
    const unsigned short* __restrict__ Bt,
    const float* __restrict__ sc, const float* __restrict__ bi,
    float* __restrict__ C)                  // [544][6400]
{
    __shared__ __align__(16) unsigned char smem[131072];   // 2 stages x 64 KB
    const int t = threadIdx.x;
    const int mblk = blockIdx.x, nblk = blockIdx.y;
    const int m0 = mblk * 128, n0 = nblk * 128;
    const int lane = t & 63, w = t >> 6;
    const int g = w >> 2, wq = w & 3;
    const int wm = wq >> 1, wn = wq & 1;
    const int row16 = lane & 15, quad = lane >> 4;

    f32x4 acc[4][4] = {};

    const unsigned short* gAbase = At + (((size_t)mblk * NKT) << 14);
    const unsigned short* gBbase = Bt + (((size_t)nblk * NKT) << 14);

    #define STAGE(kt, s)                                                      \
    {                                                                         \
        unsigned short* As_ = (unsigned short*)(smem + (s) * 65536);          \
        unsigned short* Bs_ = As_ + 16384;                                    \
        const unsigned short* ga = gAbase + ((size_t)(kt) << 14);             \
        const unsigned short* gb = gBbase + ((size_t)(kt) << 14);             \
        _Pragma("unroll")                                                     \
        for (int j = 0; j < 4; ++j) {                                         \
            async_copy16(ga + ((size_t)(j * 512 + t) << 3),                   \
                         As_ + ((size_t)(j * 512 + w * 64) << 3));            \
            async_copy16(gb + ((size_t)(j * 512 + t) << 3),                   \
                         Bs_ + ((size_t)(j * 512 + w * 64) << 3));            \
        }                                                                     \
    }

    #define COMPUTE(s)                                                        \
    {                                                                         \
        const unsigned short* As_ = (const unsigned short*)(smem + (s) * 65536);\
        const unsigned short* Bs_ = As_ + 16384;                              \
        _Pragma("unroll")                                                     \
        for (int ks = 0; ks < 2; ++ks) {                                      \
            const int kc8b = g * 8 + ks * 4 + quad;                           \
            const int sw = kc8b << 2;                                         \
            bf16x8 af[4], bfr[4];                                             \
            _Pragma("unroll")                                                 \
            for (int mt = 0; mt < 4; ++mt)                                    \
                af[mt] = *reinterpret_cast<const bf16x8*>(                    \
                    &As_[(size_t)(kc8b * 128 + ((wm * 64 + mt * 16 + row16) ^ sw)) * 8]);\
            _Pragma("unroll")                                                 \
            for (int nt = 0; nt < 4; ++nt)                                    \
                bfr[nt] = *reinterpret_cast<const bf16x8*>(                   \
                    &Bs_[(size_t)(kc8b * 128 + ((wn * 64 + nt * 16 + row16) ^ sw)) * 8]);\
            _Pragma("unroll")                                                 \
            for (int mt = 0; mt < 4; ++mt)                                    \
                _Pragma("unroll")                                             \
                for (int nt = 0; nt < 4; ++nt)                                \
                    acc[mt][nt] = __builtin_amdgcn_mfma_f32_16x16x32_bf16(    \
                        af[mt], bfr[nt], acc[mt][nt], 0, 0, 0);               \
        }                                                                     \
    }

    STAGE(0, 0);
    for (int kt = 0; kt < NKT; ++kt) {
        __syncthreads();                 // drains stage(kt); frees other buf
        if (kt + 1 < NKT) STAGE(kt + 1, (kt + 1) & 1);
        COMPUTE(kt & 1);
    }
    #undef STAGE
    #undef COMPUTE

    // merge K-groups: wave pairs (g0,wq) <- (g1,wq), 2 rounds of 2 pairs.
    float* mb = (float*)smem;                    // 8192 floats (stage0 A)
    #pragma unroll
    for (int rnd = 0; rnd < 2; ++rnd) {
        __syncthreads();
        if (g == 1 && (wq >> 1) == rnd) {
            f32x4* dst = (f32x4*)(mb + (wq & 1) * 4096);
            #pragma unroll
            for (int i = 0; i < 16; ++i)
                dst[i * 64 + lane] = acc[i >> 2][i & 3];
        }
        __syncthreads();
        if (g == 0 && (wq >> 1) == rnd) {
            const f32x4* src = (const f32x4*)(mb + (wq & 1) * 4096);
            #pragma unroll
            for (int i = 0; i < 16; ++i)
                acc[i >> 2][i & 3] += src[i * 64 + lane];
        }
    }

    if (g == 0) {
        #pragma unroll
        for (int mt = 0; mt < 4; ++mt) {
            const int mbase = m0 + wm * 64 + mt * 16 + quad * 4;
            if (mbase >= 544) continue;
            #pragma unroll
            for (int rg = 0; rg < 4; ++rg) {
                const int m = mbase + rg;
                const float s = sc[m], bbx = bi[m];
                const bool is_a = (m >= 512);
                #pragma unroll
                for (int nt = 0; nt < 4; ++nt) {
                    const int n = n0 + wn * 64 + nt * 16 + row16;
                    float v = fmaf(acc[mt][nt][rg], s, bbx);
                    if (is_a) v = 1.f / (1.f + fexp(-v));
                    C[(size_t)m * NTOT + n] = v;
                }
            }
        }
    }
}

// ---------------------------------------------------------------------------
// EM routing: 320 threads = 10 classes x 32 a-lanes, one block per batch.
// Phase A writes ln_ap[c][m]; phase B does cross-class softmax + stats.
// Wm loads explicitly software-pipelined (1-iter prefetch distance).
// ---------------------------------------------------------------------------
struct W16 { float4 a, b, c, d; };
__device__ __forceinline__ W16 loadW(const float* wp) {
    W16 r;
    r.a = reinterpret_cast<const float4*>(wp)[0];
    r.b = reinterpret_cast<const float4*>(wp)[1];
    r.c = reinterpret_cast<const float4*>(wp)[2];
    r.d = reinterpret_cast<const float4*>(wp)[3];
    return r;
}
__device__ __forceinline__ void vote16(const float* pmp, const W16& W, float* vv) {
    float pm[16];
    const float4* pr = reinterpret_cast<const float4*>(pmp);
    float4 p0 = pr[0], p1 = pr[1], p2 = pr[2], p3 = pr[3];
    pm[0]=p0.x; pm[1]=p0.y; pm[2]=p0.z; pm[3]=p0.w;
    pm[4]=p1.x; pm[5]=p1.y; pm[6]=p1.z; pm[7]=p1.w;
    pm[8]=p2.x; pm[9]=p2.y; pm[10]=p2.z; pm[11]=p2.w;
    pm[12]=p3.x; pm[13]=p3.y; pm[14]=p3.z; pm[15]=p3.w;
    const float wv[16] = {W.a.x,W.a.y,W.a.z,W.a.w, W.b.x,W.b.y,W.b.z,W.b.w,
                          W.c.x,W.c.y,W.c.z,W.c.w, W.d.x,W.d.y,W.d.z,W.d.w};
    #pragma unroll
    for (int r = 0; r < 4; ++r)
        #pragma unroll
        for (int s = 0; s < 4; ++s) {
            float av = 0.f;
            #pragma unroll
            for (int tt = 0; tt < 4; ++tt)
                av = fmaf(pm[r*4+tt], wv[tt*4+s], av);
            vv[r*4+s] = av;
        }
}

__global__ __launch_bounds__(320) void em_kernel(
    const float* __restrict__ C,
    const float* __restrict__ Wm,       // (800,10,4,4)
    const float* __restrict__ beta_u, const float* __restrict__ beta_a,
    float* __restrict__ out)            // (256,10)
{
    __shared__ __align__(16) float psh[25][32][20];   // 64 KB
    __shared__ float aush[800];
    __shared__ float lnq[NCLS][800];                  // 32 KB
    __shared__ float mu_sh[NCLS][16];
    __shared__ float i2s_sh[NCLS][16];
    __shared__ float Kc_sh[NCLS];
    __shared__ float aout_sh[NCLS];

    const int b = blockIdx.x, t = threadIdx.x;
    const int c = t >> 5, a = t & 31;

    const float* pb = C + (size_t)b * 25;
    for (int f = t; f < 12800; f += 320) {
        const int c2 = f / 25, px = f - c2 * 25;
        psh[px][c2 >> 4][c2 & 15] = pb[(size_t)c2 * NTOT + px];
    }
    const float* ab = C + (size_t)512 * NTOT + (size_t)b * 25;
    for (int f = t; f < 800; f += 320) {
        const int ci = f / 25, px = f - ci * 25;
        aush[px * 32 + ci] = ab[(size_t)ci * NTOT + px];
    }
    __syncthreads();

    const float bu = beta_u[c], ba = beta_a[c];
    const float lam_tab[3] = {0.01f * (1.f - 0.95f),
                              0.01f * (1.f - 0.95f * 0.95f),
                              0.01f * (1.f - 0.95f * 0.95f * 0.95f)};
    float muL[16], i2sL[16], KcL = 0.f;
    float S0, S1[16], S2[16];

    const float* wp0 = Wm + ((size_t)a * NCLS + c) * 16;   // + kk*5120

    #define ACCUM(rw)                                                        \
        S0 += (rw);                                                          \
        _Pragma("unroll")                                                    \
        for (int p = 0; p < 16; ++p) {                                       \
            const float rv = (rw) * vv[p];                                   \
            S1[p] += rv;                                                     \
            S2[p] = fmaf(rv, vv[p], S2[p]);                                  \
        }

    for (int it = 0; it < 3; ++it) {
        if (it > 0) {
            W16 Wc = loadW(wp0);
            for (int kk = 0; kk < 25; ++kk) {
                W16 Wn;
                if (kk < 24) Wn = loadW(wp0 + (size_t)(kk + 1) * 5120);
                float vv[16];
                vote16(&psh[kk][a][0], Wc, vv);
                float q = KcL;
                #pragma unroll
                for (int p = 0; p < 16; ++p) {
                    const float d = vv[p] - muL[p];
                    q -= d * d * i2sL[p];
                }
                lnq[c][kk * 32 + a] = q;
                Wc = Wn;
            }
            __syncthreads();
        }

        S0 = 0.f;
        #pragma unroll
        for (int p = 0; p < 16; ++p) { S1[p] = 0.f; S2[p] = 0.f; }

        {
            W16 Wc = loadW(wp0);
            for (int kk = 0; kk < 25; ++kk) {
                W16 Wn;
                if (kk < 24) Wn = loadW(wp0 + (size_t)(kk + 1) * 5120);
                float vv[16];
                vote16(&psh[kk][a][0], Wc, vv);
                const int m = kk * 32 + a;
                float rw;
                if (it == 0) {
                    rw = aush[m];
                } else {
                    float qv[NCLS];
                    #pragma unroll
                    for (int cc = 0; cc < NCLS; ++cc) qv[cc] = lnq[cc][m];
                    float mx = qv[0];
                    #pragma unroll
                    for (int cc = 1; cc < NCLS; ++cc) mx = fmaxf(mx, qv[cc]);
                    float den = 0.f;
                    #pragma unroll
                    for (int cc = 0; cc < NCLS; ++cc) den += fexp(qv[cc] - mx);
                    const float r = fexp(qv[c] - mx) * __builtin_amdgcn_rcpf(den);
                    rw = r * aush[m];
                }
                ACCUM(rw);
                Wc = Wn;
            }
        }

        #pragma unroll
        for (int off = 16; off >= 1; off >>= 1) {
            S0 += __shfl_xor(S0, off);
            #pragma unroll
            for (int p = 0; p < 16; ++p) {
                S1[p] += __shfl_xor(S1[p], off);
                S2[p] += __shfl_xor(S2[p], off);
            }
        }

        if (a == 0) {
            const float lam = lam_tab[it];
            const float s0e = S0 + 1e-12f;
            const float inv = 1.f / s0e;
            float costsum = 0.f, slg = 0.f;
            float mu_[16], sg_[16];
            #pragma unroll
            for (int p = 0; p < 16; ++p) {
                mu_[p] = S1[p] * inv;
                const float sg = (S2[p] - 2.f * mu_[p] * S1[p] + mu_[p] * mu_[p] * S0) * inv
                                 + 1e-12f;
                sg_[p] = sg;
                costsum += bu + 0.5f * flog(sg);
            }
            costsum *= S0;
            const float aout = 1.f / (1.f + fexp(-(lam * (ba - costsum))));
            aout_sh[c] = aout;
            if (it < 2) {
                #pragma unroll
                for (int p = 0; p < 16; ++p) {
                    mu_sh[c][p] = mu_[p];
                    i2s_sh[c][p] = 0.5f / sg_[p];
                    slg += flog(sg_[p] * LN2PI_F);
                }
                Kc_sh[c] = flog(aout) - 0.5f * slg;
            }
        }
        __syncthreads();
        if (it < 2) {
            #pragma unroll
            for (int p = 0; p < 16; ++p) { muL[p] = mu_sh[c][p]; i2sL[p] = i2s_sh[c][p]; }
            KcL = Kc_sh[c];
        }
    }

    if (t < NCLS) {
        float s = 0.f;
        #pragma unroll
        for (int cc = 0; cc < NCLS; ++cc) s += aout_sh[cc];
        out[b * NCLS + t] = flog(aout_sh[t] / s);
    }
    #undef ACCUM
}

// ---------------------------------------------------------------------------
extern "C" void kernel_launch(void* const* d_in, const int* in_sizes, int n_in,
                              void* d_out, int out_size, void* d_ws, size_t ws_size,
                              hipStream_t stream) {
    const float* x      = (const float*)d_in[0];
    const float* w_a    = (const float*)d_in[1];
    const float* w_pose = (const float*)d_in[2];
    const float* bn_a_g = (const float*)d_in[3];
    const float* bn_a_b = (const float*)d_in[4];
    const float* bn_a_m = (const float*)d_in[5];
    const float* bn_a_v = (const float*)d_in[6];
    const float* bn_p_g = (const float*)d_in[7];
    const float* bn_p_b = (const float*)d_in[8];
    const float* bn_p_m = (const float*)d_in[9];
    const float* bn_p_v = (const float*)d_in[10];
    const float* Wm     = (const float*)d_in[11];
    const float* beta_u = (const float*)d_in[12];
    const float* beta_a = (const float*)d_in[13];
    float* out = (float*)d_out;

    char* p = (char*)d_ws;
    unsigned short* At = (unsigned short*)p;  p += (size_t)MPAD * KDIM * 2;
    unsigned short* Bt = (unsigned short*)p;  p += (size_t)NTOT * KDIM * 2;
    float* C  = (float*)p;                    p += (size_t)544 * NTOT * 4;
    float* sc = (float*)p;                    p += MPAD * 4;
    float* bi = (float*)p;                    p += MPAD * 4;

    pack_a_kernel<<<5 * NKT, 256, 0, stream>>>(w_pose, w_a,
                                               bn_p_g, bn_p_b, bn_p_m, bn_p_v,
                                               bn_a_g, bn_a_b, bn_a_m, bn_a_v,
                                               At, sc, bi);
    pack_b_kernel<<<256, 256, 0, stream>>>(x, Bt);
    dim3 gg(MPAD / 128, NTOT / 128);
    gemm_kernel<<<gg, 512, 0, stream>>>(At, Bt, sc, bi, C);
    em_kernel<<<256, 320, 0, stream>>>(C, Wm, beta_u, beta_a, out);
}

// Round 5
// 270.137 us; speedup vs baseline: 8.7198x; 1.0877x over previous
//
#include <hip/hip_runtime.h>
#include <math.h>

#define CIN 512
#define NCLS 10
#define KDIM 4608            // 512*9
#define NTOT 6400            // 256*25
#define MPAD 640
#define BK 128
#define NKT 36               // KDIM/BK
#define NABLK (5 * NKT)      // 180 A-tile blocks in pack_a
#define LN2PI_F 1.8378770664093453f

typedef __attribute__((ext_vector_type(8))) short bf16x8;
typedef __attribute__((ext_vector_type(4))) float f32x4;

typedef const __attribute__((address_space(1))) void* gas_ptr;
typedef __attribute__((address_space(3))) void* las_ptr;

__device__ __forceinline__ void async_copy16(const void* g, void* l) {
    __builtin_amdgcn_global_load_lds((gas_ptr)g, (las_ptr)l, 16, 0, 0);
}

__device__ __forceinline__ unsigned short f2bf(float f) {
    unsigned int u = __float_as_uint(f);
    u = (u + 0x7fffu + ((u >> 16) & 1u)) >> 16;   // RNE
    return (unsigned short)u;
}
__device__ __forceinline__ float fexp(float x) { return __expf(x); }
__device__ __forceinline__ float flog(float x) { return __logf(x); }

// ---------------------------------------------------------------------------
// pack_a: blocks [0,180): weights fp32 -> bf16 pre-tiled for the GEMM's LDS
// staging order. Blocks [180, 243): Wm fp32 -> bf16 (for em_kernel).
// Block 0 additionally computes the folded BN scale/bias.
// ---------------------------------------------------------------------------
__global__ __launch_bounds__(256) void pack_a_kernel(
    const float* __restrict__ w_pose, const float* __restrict__ w_a,
    const float* __restrict__ bn_p_g, const float* __restrict__ bn_p_b,
    const float* __restrict__ bn_p_m, const float* __restrict__ bn_p_v,
    const float* __restrict__ bn_a_g, const float* __restrict__ bn_a_b,
    const float* __restrict__ bn_a_m, const float* __restrict__ bn_a_v,
    const float* __restrict__ Wm,
    unsigned short* __restrict__ At, unsigned short* __restrict__ Wmb,
    float* __restrict__ sc, float* __restrict__ bi)
{
    const int blk = blockIdx.x;
    const int t = threadIdx.x;

    if (blk >= NABLK) {                          // ---- Wm bf16 packing ----
        const int chunk = (blk - NABLK) * 256 + t;   // 8 floats per chunk
        if (chunk < 16000) {
            const float4* s4 = reinterpret_cast<const float4*>(Wm + (size_t)chunk * 8);
            float4 x0 = s4[0], x1 = s4[1];
            int4 o;
            o.x = (int)f2bf(x0.x) | ((int)f2bf(x0.y) << 16);
            o.y = (int)f2bf(x0.z) | ((int)f2bf(x0.w) << 16);
            o.z = (int)f2bf(x1.x) | ((int)f2bf(x1.y) << 16);
            o.w = (int)f2bf(x1.z) | ((int)f2bf(x1.w) << 16);
            reinterpret_cast<int4*>(Wmb + (size_t)chunk * 8)[0] = o;
        }
        return;
    }

    const int mblk = blk / NKT;
    if (blk == 0) {
        for (int i = t; i < MPAD; i += 256) {
            float s = 0.f, b = 0.f;
            if (i < 512) {
                s = bn_p_g[i] / sqrtf(bn_p_v[i] + 1e-5f);
                b = bn_p_b[i] - bn_p_m[i] * s;
            } else if (i < 544) {
                const int j = i - 512;
                s = bn_a_g[j] / sqrtf(bn_a_v[j] + 1e-5f);
                b = bn_a_b[j] - bn_a_m[j] * s;
            }
            sc[i] = s; bi[i] = b;
        }
    }

    const int kt = blk - mblk * NKT;
    #pragma unroll
    for (int j = 0; j < 8; ++j) {
        const int c = t + j * 256;               // 0..2047
        const int kc8 = c >> 7, slot = c & 127;
        const int row = mblk * 128 + (slot ^ (kc8 << 2));
        const int k0 = (kt * 16 + kc8) * 8;
        float v[8] = {0.f,0.f,0.f,0.f,0.f,0.f,0.f,0.f};
        if (row < 512) {
            const float4* s4 = reinterpret_cast<const float4*>(w_pose + (size_t)row * KDIM + k0);
            float4 x0 = s4[0], x1 = s4[1];
            v[0]=x0.x; v[1]=x0.y; v[2]=x0.z; v[3]=x0.w;
            v[4]=x1.x; v[5]=x1.y; v[6]=x1.z; v[7]=x1.w;
        } else if (row < 544) {
            const float4* s4 = reinterpret_cast<const float4*>(w_a + (size_t)(row - 512) * KDIM + k0);
            float4 x0 = s4[0], x1 = s4[1];
            v[0]=x0.x; v[1]=x0.y; v[2]=x0.z; v[3]=x0.w;
            v[4]=x1.x; v[5]=x1.y; v[6]=x1.z; v[7]=x1.w;
        }
        int4 o;
        o.x = (int)f2bf(v[0]) | ((int)f2bf(v[1]) << 16);
        o.y = (int)f2bf(v[2]) | ((int)f2bf(v[3]) << 16);
        o.z = (int)f2bf(v[4]) | ((int)f2bf(v[5]) << 16);
        o.w = (int)f2bf(v[6]) | ((int)f2bf(v[7]) << 16);
        reinterpret_cast<int4*>(At + ((((size_t)blk) << 11) + c) * 8)[0] = o;
    }
}

// ---------------------------------------------------------------------------
// pack_b: im2col fp32->bf16 into the GEMM pre-tiled layout. 1024 threads.
// ---------------------------------------------------------------------------
__global__ __launch_bounds__(1024) void pack_b_kernel(
    const float* __restrict__ x, unsigned short* __restrict__ Bt)
{
    __shared__ __align__(16) float xs[CIN * 25];
    const int b = blockIdx.x;
    const int t = threadIdx.x;
    const float4* xb = reinterpret_cast<const float4*>(x + (size_t)b * (CIN * 25));
    for (int f4 = t; f4 < (CIN * 25) / 4; f4 += 1024)
        reinterpret_cast<float4*>(xs)[f4] = xb[f4];
    __syncthreads();

    for (int w = t; w < 25 * (KDIM / 8); w += 1024) {
        const int px = w / (KDIM / 8);
        const int ch = w - px * (KDIM / 8);
        const int py = px / 5, qx = px % 5;
        const int k0 = ch * 8;
        unsigned short v[8];
        #pragma unroll
        for (int j = 0; j < 8; ++j) {
            const int k = k0 + j;
            const int ci = k / 9;
            const int kk = k - ci * 9;
            const int dy = kk / 3, dx = kk - dy * 3;
            const int yy = py + dy - 1, xx = qx + dx - 1;
            const bool ok = (yy >= 0) & (yy < 5) & (xx >= 0) & (xx < 5);
            v[j] = ok ? f2bf(xs[ci * 25 + yy * 5 + xx]) : (unsigned short)0;
        }
        int4 o;
        o.x = (int)v[0] | ((int)v[1] << 16);
        o.y = (int)v[2] | ((int)v[3] << 16);
        o.z = (int)v[4] | ((int)v[5] << 16);
        o.w = (int)v[6] | ((int)v[7] << 16);
        const int n = b * 25 + px;
        const int nblk = n >> 7, nr = n & 127;
        const int kt = k0 >> 7;
        const int kc8 = (k0 >> 3) & 15;
        const int c = kc8 * 128 + (nr ^ (kc8 << 2));
        reinterpret_cast<int4*>(Bt + ((((size_t)(nblk * NKT + kt)) << 11) + c) * 8)[0] = o;
    }
}

// ---------------------------------------------------------------------------
// gemm: unchanged from R4 (128x128, 2 K-groups x (2x2) waves, 64x64 wave
// tile, BK=128 double-buffered, pre-tiled coalesced staging).
// ---------------------------------------------------------------------------
__global__ __launch_bounds__(512) void gemm_kernel(
    const unsigned short* __restrict__ At,
    const unsigned short* __restrict__ Bt,
    const float* __restrict__ sc, const float* __restrict__ bi,
    float* __restrict__ C)                  // [544][6400]
{
    __shared__ __align__(16) unsigned char smem[131072];
    const int t = threadIdx.x;
    const int mblk = blockIdx.x, nblk = blockIdx.y;
    const int m0 = mblk * 128, n0 = nblk * 128;
    const int lane = t & 63, w = t >> 6;
    const int g = w >> 2, wq = w & 3;
    const int wm = wq >> 1, wn = wq & 1;
    const int row16 = lane & 15, quad = lane >> 4;

    f32x4 acc[4][4] = {};

    const unsigned short* gAbase = At + (((size_t)mblk * NKT) << 14);
    const unsigned short* gBbase = Bt + (((size_t)nblk * NKT) << 14);

    #define STAGE(kt, s)                                                      \
    {                                                                         \
        unsigned short* As_ = (unsigned short*)(smem + (s) * 65536);          \
        unsigned short* Bs_ = As_ + 16384;                                    \
        const unsigned short* ga = gAbase + ((size_t)(kt) << 14);             \
        const unsigned short* gb = gBbase + ((size_t)(kt) << 14);             \
        _Pragma("unroll")                                                     \
        for (int j = 0; j < 4; ++j) {                                         \
            async_copy16(ga + ((size_t)(j * 512 + t) << 3),                   \
                         As_ + ((size_t)(j * 512 + w * 64) << 3));            \
            async_copy16(gb + ((size_t)(j * 512 + t) << 3),                   \
                         Bs_ + ((size_t)(j * 512 + w * 64) << 3));            \
        }                                                                     \
    }

    #define COMPUTE(s)                                                        \
    {                                                                         \
        const unsigned short* As_ = (const unsigned short*)(smem + (s) * 65536);\
        const unsigned short* Bs_ = As_ + 16384;                              \
        _Pragma("unroll")                                                     \
        for (int ks = 0; ks < 2; ++ks) {                                      \
            const int kc8b = g * 8 + ks * 4 + quad;                           \
            const int sw = kc8b << 2;                                         \
            bf16x8 af[4], bfr[4];                                             \
            _Pragma("unroll")                                                 \
            for (int mt = 0; mt < 4; ++mt)                                    \
                af[mt] = *reinterpret_cast<const bf16x8*>(                    \
                    &As_[(size_t)(kc8b * 128 + ((wm * 64 + mt * 16 + row16) ^ sw)) * 8]);\
            _Pragma("unroll")                                                 \
            for (int nt = 0; nt < 4; ++nt)                                    \
                bfr[nt] = *reinterpret_cast<const bf16x8*>(                   \
                    &Bs_[(size_t)(kc8b * 128 + ((wn * 64 + nt * 16 + row16) ^ sw)) * 8]);\
            _Pragma("unroll")                                                 \
            for (int mt = 0; mt < 4; ++mt)                                    \
                _Pragma("unroll")                                             \
                for (int nt = 0; nt < 4; ++nt)                                \
                    acc[mt][nt] = __builtin_amdgcn_mfma_f32_16x16x32_bf16(    \
                        af[mt], bfr[nt], acc[mt][nt], 0, 0, 0);               \
        }                                                                     \
    }

    STAGE(0, 0);
    for (int kt = 0; kt < NKT; ++kt) {
        __syncthreads();
        if (kt + 1 < NKT) STAGE(kt + 1, (kt + 1) & 1);
        COMPUTE(kt & 1);
    }
    #undef STAGE
    #undef COMPUTE

    float* mb = (float*)smem;
    #pragma unroll
    for (int rnd = 0; rnd < 2; ++rnd) {
        __syncthreads();
        if (g == 1 && (wq >> 1) == rnd) {
            f32x4* dst = (f32x4*)(mb + (wq & 1) * 4096);
            #pragma unroll
            for (int i = 0; i < 16; ++i)
                dst[i * 64 + lane] = acc[i >> 2][i & 3];
        }
        __syncthreads();
        if (g == 0 && (wq >> 1) == rnd) {
            const f32x4* src = (const f32x4*)(mb + (wq & 1) * 4096);
            #pragma unroll
            for (int i = 0; i < 16; ++i)
                acc[i >> 2][i & 3] += src[i * 64 + lane];
        }
    }

    if (g == 0) {
        #pragma unroll
        for (int mt = 0; mt < 4; ++mt) {
            const int mbase = m0 + wm * 64 + mt * 16 + quad * 4;
            if (mbase >= 544) continue;
            #pragma unroll
            for (int rg = 0; rg < 4; ++rg) {
                const int m = mbase + rg;
                const float s = sc[m], bbx = bi[m];
                const bool is_a = (m >= 512);
                #pragma unroll
                for (int nt = 0; nt < 4; ++nt) {
                    const int n = n0 + wn * 64 + nt * 16 + row16;
                    float v = fmaf(acc[mt][nt][rg], s, bbx);
                    if (is_a) v = 1.f / (1.f + fexp(-v));
                    C[(size_t)m * NTOT + n] = v;
                }
            }
        }
    }
}

// ---------------------------------------------------------------------------
// EM routing: 640 threads = 2 kk-halves x 10 classes x 32 a-lanes, one block
// per batch. Wm in bf16 (halved L2/L3 traffic). Cross-half merge via LDS.
// ---------------------------------------------------------------------------
__device__ __forceinline__ void loadW_bf(const unsigned short* wp, float* wv) {
    const int4* q = reinterpret_cast<const int4*>(wp);
    const int4 q0 = q[0], q1 = q[1];
    const unsigned int u[8] = {(unsigned)q0.x,(unsigned)q0.y,(unsigned)q0.z,(unsigned)q0.w,
                               (unsigned)q1.x,(unsigned)q1.y,(unsigned)q1.z,(unsigned)q1.w};
    #pragma unroll
    for (int i = 0; i < 8; ++i) {
        wv[2*i]   = __uint_as_float(u[i] << 16);
        wv[2*i+1] = __uint_as_float(u[i] & 0xFFFF0000u);
    }
}

__device__ __forceinline__ void vote16(const float* pmp, const float* wv, float* vv) {
    float pm[16];
    const float4* pr = reinterpret_cast<const float4*>(pmp);
    float4 p0 = pr[0], p1 = pr[1], p2 = pr[2], p3 = pr[3];
    pm[0]=p0.x; pm[1]=p0.y; pm[2]=p0.z; pm[3]=p0.w;
    pm[4]=p1.x; pm[5]=p1.y; pm[6]=p1.z; pm[7]=p1.w;
    pm[8]=p2.x; pm[9]=p2.y; pm[10]=p2.z; pm[11]=p2.w;
    pm[12]=p3.x; pm[13]=p3.y; pm[14]=p3.z; pm[15]=p3.w;
    #pragma unroll
    for (int r = 0; r < 4; ++r)
        #pragma unroll
        for (int s = 0; s < 4; ++s) {
            float av = 0.f;
            #pragma unroll
            for (int tt = 0; tt < 4; ++tt)
                av = fmaf(pm[r*4+tt], wv[tt*4+s], av);
            vv[r*4+s] = av;
        }
}

__global__ __launch_bounds__(640) void em_kernel(
    const float* __restrict__ C,
    const unsigned short* __restrict__ Wmb,   // (800,10,16) bf16
    const float* __restrict__ beta_u, const float* __restrict__ beta_a,
    float* __restrict__ out)                  // (256,10)
{
    __shared__ __align__(16) float psh[25][32][20];   // 64 KB
    __shared__ float aush[800];
    __shared__ float lnq[NCLS][800];                  // 32 KB
    __shared__ float redsh[NCLS][34];
    __shared__ float mu_sh[NCLS][16];
    __shared__ float i2s_sh[NCLS][16];
    __shared__ float Kc_sh[NCLS];
    __shared__ float aout_sh[NCLS];

    const int b = blockIdx.x, t = threadIdx.x;
    const int h = t >= 320 ? 1 : 0;
    const int th = t - h * 320;
    const int c = th >> 5, a = th & 31;
    const int kkA = h ? 13 : 0, kkB = h ? 25 : 13;

    const float* pb = C + (size_t)b * 25;
    for (int f = t; f < 12800; f += 640) {
        const int c2 = f / 25, px = f - c2 * 25;
        psh[px][c2 >> 4][c2 & 15] = pb[(size_t)c2 * NTOT + px];
    }
    const float* ab = C + (size_t)512 * NTOT + (size_t)b * 25;
    for (int f = t; f < 800; f += 640) {
        const int ci = f / 25, px = f - ci * 25;
        aush[px * 32 + ci] = ab[(size_t)ci * NTOT + px];
    }
    __syncthreads();

    const float bu = beta_u[c], ba = beta_a[c];
    const float lam_tab[3] = {0.01f * (1.f - 0.95f),
                              0.01f * (1.f - 0.95f * 0.95f),
                              0.01f * (1.f - 0.95f * 0.95f * 0.95f)};
    float muL[16], i2sL[16], KcL = 0.f;
    float S0, S1[16], S2[16];

    // Wmb entry for (m = kk*32 + a, c): 16 bf16 = 32 B
    const unsigned short* wbase = Wmb + ((size_t)a * NCLS + c) * 16;  // + kk*5120

    for (int it = 0; it < 3; ++it) {
        if (it > 0) {
            for (int kk = kkA; kk < kkB; ++kk) {
                float wv[16], vv[16];
                loadW_bf(wbase + (size_t)kk * 5120, wv);
                vote16(&psh[kk][a][0], wv, vv);
                float q = KcL;
                #pragma unroll
                for (int p = 0; p < 16; ++p) {
                    const float d = vv[p] - muL[p];
                    q -= d * d * i2sL[p];
                }
                lnq[c][kk * 32 + a] = q;
            }
            __syncthreads();
        }

        S0 = 0.f;
        #pragma unroll
        for (int p = 0; p < 16; ++p) { S1[p] = 0.f; S2[p] = 0.f; }

        for (int kk = kkA; kk < kkB; ++kk) {
            float wv[16], vv[16];
            loadW_bf(wbase + (size_t)kk * 5120, wv);
            vote16(&psh[kk][a][0], wv, vv);
            const int m = kk * 32 + a;
            float rw;
            if (it == 0) {
                rw = aush[m];
            } else {
                float qv[NCLS];
                #pragma unroll
                for (int cc = 0; cc < NCLS; ++cc) qv[cc] = lnq[cc][m];
                float mx = qv[0];
                #pragma unroll
                for (int cc = 1; cc < NCLS; ++cc) mx = fmaxf(mx, qv[cc]);
                float den = 0.f;
                #pragma unroll
                for (int cc = 0; cc < NCLS; ++cc) den += fexp(qv[cc] - mx);
                const float r = fexp(qv[c] - mx) * __builtin_amdgcn_rcpf(den);
                rw = r * aush[m];
            }
            S0 += rw;
            #pragma unroll
            for (int p = 0; p < 16; ++p) {
                const float rv = rw * vv[p];
                S1[p] += rv;
                S2[p] = fmaf(rv, vv[p], S2[p]);
            }
        }

        // butterfly over the 32 a-lanes (within half-wave)
        #pragma unroll
        for (int off = 16; off >= 1; off >>= 1) {
            S0 += __shfl_xor(S0, off);
            #pragma unroll
            for (int p = 0; p < 16; ++p) {
                S1[p] += __shfl_xor(S1[p], off);
                S2[p] += __shfl_xor(S2[p], off);
            }
        }

        // cross-half merge
        if (h == 1 && a == 0) {
            redsh[c][0] = S0;
            #pragma unroll
            for (int p = 0; p < 16; ++p) { redsh[c][1 + p] = S1[p]; redsh[c][17 + p] = S2[p]; }
        }
        __syncthreads();
        if (h == 0 && a == 0) {
            S0 += redsh[c][0];
            #pragma unroll
            for (int p = 0; p < 16; ++p) { S1[p] += redsh[c][1 + p]; S2[p] += redsh[c][17 + p]; }

            const float lam = lam_tab[it];
            const float s0e = S0 + 1e-12f;
            const float inv = 1.f / s0e;
            float costsum = 0.f, slg = 0.f;
            float mu_[16], sg_[16];
            #pragma unroll
            for (int p = 0; p < 16; ++p) {
                mu_[p] = S1[p] * inv;
                const float sg = (S2[p] - 2.f * mu_[p] * S1[p] + mu_[p] * mu_[p] * S0) * inv
                                 + 1e-12f;
                sg_[p] = sg;
                costsum += bu + 0.5f * flog(sg);
            }
            costsum *= S0;
            const float aout = 1.f / (1.f + fexp(-(lam * (ba - costsum))));
            aout_sh[c] = aout;
            if (it < 2) {
                #pragma unroll
                for (int p = 0; p < 16; ++p) {
                    mu_sh[c][p] = mu_[p];
                    i2s_sh[c][p] = 0.5f / sg_[p];
                    slg += flog(sg_[p] * LN2PI_F);
                }
                Kc_sh[c] = flog(aout) - 0.5f * slg;
            }
        }
        __syncthreads();
        if (it < 2) {
            #pragma unroll
            for (int p = 0; p < 16; ++p) { muL[p] = mu_sh[c][p]; i2sL[p] = i2s_sh[c][p]; }
            KcL = Kc_sh[c];
        }
    }

    if (t < NCLS) {
        float s = 0.f;
        #pragma unroll
        for (int cc = 0; cc < NCLS; ++cc) s += aout_sh[cc];
        out[b * NCLS + t] = flog(aout_sh[t] / s);
    }
}

// ---------------------------------------------------------------------------
extern "C" void kernel_launch(void* const* d_in, const int* in_sizes, int n_in,
                              void* d_out, int out_size, void* d_ws, size_t ws_size,
                              hipStream_t stream) {
    const float* x      = (const float*)d_in[0];
    const float* w_a    = (const float*)d_in[1];
    const float* w_pose = (const float*)d_in[2];
    const float* bn_a_g = (const float*)d_in[3];
    const float* bn_a_b = (const float*)d_in[4];
    const float* bn_a_m = (const float*)d_in[5];
    const float* bn_a_v = (const float*)d_in[6];
    const float* bn_p_g = (const float*)d_in[7];
    const float* bn_p_b = (const float*)d_in[8];
    const float* bn_p_m = (const float*)d_in[9];
    const float* bn_p_v = (const float*)d_in[10];
    const float* Wm     = (const float*)d_in[11];
    const float* beta_u = (const float*)d_in[12];
    const float* beta_a = (const float*)d_in[13];
    float* out = (float*)d_out;

    char* p = (char*)d_ws;
    unsigned short* At  = (unsigned short*)p;  p += (size_t)MPAD * KDIM * 2;
    unsigned short* Bt  = (unsigned short*)p;  p += (size_t)NTOT * KDIM * 2;
    unsigned short* Wmb = (unsigned short*)p;  p += (size_t)800 * NCLS * 16 * 2;
    float* C  = (float*)p;                     p += (size_t)544 * NTOT * 4;
    float* sc = (float*)p;                     p += MPAD * 4;
    float* bi = (float*)p;                     p += MPAD * 4;

    pack_a_kernel<<<NABLK + 63, 256, 0, stream>>>(w_pose, w_a,
                                                  bn_p_g, bn_p_b, bn_p_m, bn_p_v,
                                                  bn_a_g, bn_a_b, bn_a_m, bn_a_v,
                                                  Wm, At, Wmb, sc, bi);
    pack_b_kernel<<<256, 1024, 0, stream>>>(x, Bt);
    dim3 gg(MPAD / 128, NTOT / 128);
    gemm_kernel<<<gg, 512, 0, stream>>>(At, Bt, sc, bi, C);
    em_kernel<<<256, 640, 0, stream>>>(C, Wmb, beta_u, beta_a, out);
}